// Round 3
// baseline (281.959 us; speedup 1.0000x reference)
//
#include <hip/hip_runtime.h>
#include <math.h>

typedef float f32x4 __attribute__((ext_vector_type(4)));

constexpr int kB = 8;
constexpr int kS = 4096;
constexpr int kF = 128;
constexpr int kT = 16;
constexpr int kNCHUNK = 256;           // S-chunks for the partial reduction (8 blocks/CU)
constexpr int kSCHUNK = kS / kNCHUNK;  // 16 s-steps per chunk

// ---------------- Kernel A1: partial sums of diff / diff^2 per (chunk,b,f) ----
// UNCHANGED (round-2, bit-exact).
__global__ __launch_bounds__(128) void std_partial_kernel(
    const float* __restrict__ x, double* __restrict__ psum, double* __restrict__ psq) {
    const int b = blockIdx.x / kNCHUNK;
    const int c = blockIdx.x % kNCHUNK;
    const int f = threadIdx.x;  // 0..127
    const long base = ((long)(b * kS + c * kSCHUNK)) * kF + f;
    float prev = (c == 0) ? x[(long)b * kS * kF + f] : x[base - kF];
    double s1 = 0.0, s2 = 0.0;
    #pragma unroll
    for (int j = 0; j < kSCHUNK; ++j) {
        float cur = x[base + (long)j * kF];
        float d = cur - prev;   // exact f32 diff, matches reference bit-for-bit
        s1 += (double)d;
        s2 += (double)d * (double)d;
        prev = cur;
    }
    const int o = c * (kB * kF) + b * kF + f;
    psum[o] = s1;
    psq[o]  = s2;
}

// ---------------- Kernel A2: finish std (1024 blocks x 1 wave) ---------------
// UNCHANGED (round-2, bit-exact).
__global__ __launch_bounds__(64) void std_finish_kernel(
    const double* __restrict__ psum, const double* __restrict__ psq,
    float* __restrict__ denom) {
    const int i = blockIdx.x;        // 0..kB*kF-1
    const int lane = threadIdx.x;    // 0..63
    double s1 = 0.0, s2 = 0.0;
    #pragma unroll
    for (int j = 0; j < kNCHUNK / 64; ++j) {
        const long o = (long)(lane + j * 64) * (kB * kF) + i;
        s1 += psum[o];
        s2 += psq[o];
    }
    #pragma unroll
    for (int m = 32; m >= 1; m >>= 1) {
        s1 += __shfl_xor(s1, m, 64);
        s2 += __shfl_xor(s2, m, 64);
    }
    if (lane == 0) {
        const double mean = s1 / (double)kS;
        double var = s2 / (double)kS - mean * mean;
        if (var < 0.0) var = 0.0;
        const float stdf = (float)sqrt(var);   // double->f32 once, like np.std
        denom[i] = stdf + 1e-8f;               // f32 add, matches (std + EPS)
    }
}

// ---------------- Fallback: direct std if ws too small -----------------------
__global__ __launch_bounds__(128) void std_direct_kernel(
    const float* __restrict__ x, float* __restrict__ denom) {
    const int b = blockIdx.x;
    const int f = threadIdx.x;
    const long base = (long)b * kS * kF + f;
    float prev = x[base];
    double s1 = 0.0, s2 = 0.0;
    for (int s = 0; s < kS; ++s) {
        float cur = x[base + (long)s * kF];
        float d = cur - prev;
        s1 += (double)d;
        s2 += (double)d * (double)d;
        prev = cur;
    }
    const double mean = s1 / (double)kS;
    double var = s2 / (double)kS - mean * mean;
    if (var < 0.0) var = 0.0;
    denom[b * kF + f] = (float)sqrt(var) + 1e-8f;
}

// ---------------- Kernel Z: pure fill of the 5 silent t-slices ---------------
// t%3==2 -> t in {2,5,8,11,14}: 8 b x 5 t = 40 slices x 2 MB = 83.9 MB of
// zeros, no data dependency. Structured exactly like the 6.3 TB/s rocclr
// fill: grid-stride, many plain f32x4 stores per thread, contiguous per wave.
__global__ __launch_bounds__(256) void silent_fill_kernel(float* __restrict__ out) {
    constexpr long kSliceQ = (long)kS * kF / 4;   // 131072 f32x4 per (b,t) slice
    constexpr long kTotal  = 40 * kSliceQ;
    f32x4 z;
    z[0] = 0.0f; z[1] = 0.0f; z[2] = 0.0f; z[3] = 0.0f;
    f32x4* out4 = (f32x4*)out;
    const long stride = (long)gridDim.x * 256;
    for (long j = (long)blockIdx.x * 256 + threadIdx.x; j < kTotal; j += stride) {
        const int  sl  = (int)(j >> 17);      // 0..39 (slice)
        const long pos = j & (kSliceQ - 1);
        const int  b   = sl / 5;
        const int  t   = 3 * (sl - b * 5) + 2;  // 2,5,8,11,14
        out4[(((long)(b * kT + t)) << 17) + pos] = z;
    }
}

// ---------------- Kernel B: active writer, 1 read -> 11 stores ---------------
// One thread per (b,s,f4). x read ONCE total (17 MB); pos/neg computed once
// with the exact f32 division of the reference; stored to the 6 pos + 5 neg
// t-slices at 2 MB stride (round-0 proved t-strided stores run at the same
// rate as linear).
__global__ __launch_bounds__(256) void spike_active_kernel(
    const float* __restrict__ x, const float* __restrict__ denom,
    float* __restrict__ out) {
    const int tid = threadIdx.x;
    const int f4  = tid & 31;        // float4 index along F
    const int row = tid >> 5;        // 0..7 local s
    const int b   = blockIdx.x >> 9; // 512 s-groups per b
    const int s   = (blockIdx.x & 511) * 8 + row;

    const long inoff = ((long)(b * kS + s)) * kF + f4 * 4;
    const f32x4 cur  = *(const f32x4*)(x + inoff);
    const f32x4 prev = (s == 0) ? cur : *(const f32x4*)(x + inoff - kF);
    const f32x4 dn   = *(const f32x4*)(denom + b * kF + f4 * 4);

    f32x4 pos, neg;
    #pragma unroll
    for (int k = 0; k < 4; ++k) {
        const float nd = (cur[k] - prev[k]) / dn[k];  // f32 div, like reference
        pos[k] = ( nd >= 0.1f) ? 1.0f : 0.0f;
        neg[k] = (-nd >= 0.1f) ? 1.0f : 0.0f;
    }

    float* o = out + (((long)b * kT) * kS + s) * kF + f4 * 4;
    const long ts = (long)kS * kF;   // 2 MB between t-slices
    #pragma unroll
    for (int t = 0; t < kT; t += 3) *(f32x4*)(o + (long)t * ts) = pos;  // 0,3,..,15
    #pragma unroll
    for (int t = 1; t < kT; t += 3) *(f32x4*)(o + (long)t * ts) = neg;  // 1,4,..,13
}

extern "C" void kernel_launch(void* const* d_in, const int* in_sizes, int n_in,
                              void* d_out, int out_size, void* d_ws, size_t ws_size,
                              hipStream_t stream) {
    const float* x = (const float*)d_in[0];
    float* out = (float*)d_out;

    // ws layout: [0,4KB) denom floats (1024); then 8B-aligned partial doubles
    float* denom = (float*)d_ws;
    double* psum = (double*)((char*)d_ws + 4096);
    double* psq  = psum + (size_t)kNCHUNK * kB * kF;
    const size_t needed = 4096 + 2ull * kNCHUNK * kB * kF * sizeof(double);

    // Silent slices first: no dependency on std.
    silent_fill_kernel<<<2048, 256, 0, stream>>>(out);

    if (ws_size >= needed) {
        std_partial_kernel<<<kB * kNCHUNK, 128, 0, stream>>>(x, psum, psq);
        std_finish_kernel<<<kB * kF, 64, 0, stream>>>(psum, psq, denom);
    } else {
        std_direct_kernel<<<kB, 128, 0, stream>>>(x, denom);
    }

    // Active slices: 8 b x 512 s-groups = 4096 blocks x 256 threads.
    spike_active_kernel<<<kB * (kS / 8), 256, 0, stream>>>(x, denom, out);
}